// Round 1
// 1305.665 us; speedup vs baseline: 1.0217x; 1.0217x over previous
//
#include <hip/hip_runtime.h>
#include <hip/hip_bf16.h>
#include <math.h>

#define R_ROIS 300
#define NCLS 81
#define RCNN_DIN 4096
#define K_FC6 25088
#define FEAT_H 40
#define FEAT_W 40

typedef __attribute__((ext_vector_type(8))) short bf16x8;
typedef __attribute__((ext_vector_type(4))) float f32x4;
typedef __attribute__((ext_vector_type(8))) unsigned short ushort8;

__device__ inline unsigned short f2bf(float x) {
  union { float f; unsigned u; } v;
  v.f = x;
  unsigned r = v.u + 0x7fff + ((v.u >> 16) & 1);  // RNE
  return (unsigned short)(r >> 16);
}

// ---------------------------------------------------------------------------
// conv1 direct (tiny CIN=3): stride-2 3x3, SAME, bias+relu
// ---------------------------------------------------------------------------
template <int CIN, int COPT>
__global__ __launch_bounds__(256) void conv_s2_relu(
    const float* __restrict__ in, const float* __restrict__ w,
    const float* __restrict__ bias, float* __restrict__ out,
    int Hin, int Win, int Hout, int Wout) {
  int pix = blockIdx.x * blockDim.x + threadIdx.x;
  int npix = Hout * Wout;
  if (pix >= npix) return;
  int co0 = blockIdx.y * COPT;
  int oy = pix / Wout, ox = pix % Wout;

  float acc[COPT];
#pragma unroll
  for (int j = 0; j < COPT; ++j) acc[j] = bias[co0 + j];

  for (int cin = 0; cin < CIN; ++cin) {
    const float* ip = in + cin * Hin * Win;
    const float* wp = w + (co0 * CIN + cin) * 9;
#pragma unroll
    for (int ky = 0; ky < 3; ++ky) {
      int iy = oy * 2 + ky;
      if (iy >= Hin) continue;
#pragma unroll
      for (int kx = 0; kx < 3; ++kx) {
        int ix = ox * 2 + kx;
        if (ix >= Win) continue;
        float v = ip[iy * Win + ix];
#pragma unroll
        for (int j = 0; j < COPT; ++j)
          acc[j] = fmaf(v, wp[j * CIN * 9 + ky * 3 + kx], acc[j]);
      }
    }
  }
#pragma unroll
  for (int j = 0; j < COPT; ++j)
    out[(co0 + j) * npix + pix] = fmaxf(acc[j], 0.0f);
}

// ---------------------------------------------------------------------------
// im2col (stride-2 3x3 SAME), fp32 in -> bf16 col[pix][cin*9+q]
// ---------------------------------------------------------------------------
__global__ __launch_bounds__(256) void im2col_bf16(
    const float* __restrict__ in, unsigned short* __restrict__ col,
    int Cin, int Hin, int Win, int Hout, int Wout) {
  int idx = blockIdx.x * blockDim.x + threadIdx.x;
  int npix = Hout * Wout;
  if (idx >= npix * Cin) return;
  int pix = idx % npix;  // consecutive threads -> consecutive ox (read coalesce)
  int cin = idx / npix;
  int oy = pix / Wout, ox = pix % Wout;
  const float* ip = in + (size_t)cin * Hin * Win;
  unsigned short* cp = col + (size_t)pix * (Cin * 9) + cin * 9;
#pragma unroll
  for (int ky = 0; ky < 3; ++ky) {
    int iy = oy * 2 + ky;
#pragma unroll
    for (int kx = 0; kx < 3; ++kx) {
      int ix = ox * 2 + kx;
      float v = (iy < Hin && ix < Win) ? ip[iy * Win + ix] : 0.0f;
      cp[ky * 3 + kx] = f2bf(v);
    }
  }
}

// ---------------------------------------------------------------------------
// ROI align -> bf16 pooled (300, 512*7*7)
// ---------------------------------------------------------------------------
__global__ __launch_bounds__(256) void roi_align_kernel(
    const float* __restrict__ feat, const float* __restrict__ rois,
    unsigned short* __restrict__ out) {
  int idx = blockIdx.x * blockDim.x + threadIdx.x;
  if (idx >= R_ROIS * 512 * 49) return;
  int pw = idx % 7;
  int t = idx / 7;
  int ph = t % 7;
  t /= 7;
  int c = t % 512;
  int r = t / 512;

  const float SCALE = 1.0f / 16.0f;
  float x1 = rois[r * 5 + 1] * SCALE;
  float y1 = rois[r * 5 + 2] * SCALE;
  float x2 = rois[r * 5 + 3] * SCALE;
  float y2 = rois[r * 5 + 4] * SCALE;
  float bw = fmaxf(x2 - x1, 1.0f) * (1.0f / 7.0f);
  float bh = fmaxf(y2 - y1, 1.0f) * (1.0f / 7.0f);

  const float* f = feat + c * FEAT_H * FEAT_W;
  float s = 0.0f;
#pragma unroll
  for (int sy = 0; sy < 2; ++sy) {
    float gy = y1 + ((float)(ph * 2 + sy) + 0.5f) * 0.5f * bh;
    gy = fminf(fmaxf(gy, 0.0f), (float)(FEAT_H - 1));
    int y0 = (int)floorf(gy);
    float wy = gy - (float)y0;
    int y1i = min(y0 + 1, FEAT_H - 1);
#pragma unroll
    for (int sx = 0; sx < 2; ++sx) {
      float gx = x1 + ((float)(pw * 2 + sx) + 0.5f) * 0.5f * bw;
      gx = fminf(fmaxf(gx, 0.0f), (float)(FEAT_W - 1));
      int x0 = (int)floorf(gx);
      float wx = gx - (float)x0;
      int x1i = min(x0 + 1, FEAT_W - 1);
      float v00 = f[y0 * FEAT_W + x0];
      float v01 = f[y0 * FEAT_W + x1i];
      float v10 = f[y1i * FEAT_W + x0];
      float v11 = f[y1i * FEAT_W + x1i];
      s += v00 * (1.0f - wy) * (1.0f - wx) + v01 * (1.0f - wy) * wx +
           v10 * wy * (1.0f - wx) + v11 * wy * wx;
    }
  }
  out[idx] = f2bf(s * 0.25f);
}

// ---------------------------------------------------------------------------
// Generic MFMA GEMM: Cpart[s] (M,N) = A(M,K) @ B(N,K)^T over k-range s.
// A/B fp32 or bf16 in HBM; LDS bf16; 128x128 tile, BK=64, 256 thr (4 waves,
// wave tile 64x64 = 4x4 of 16x16x32). Register double-buffer prefetch of the
// next K-slab overlaps global latency with the MFMA loop. LDS rows padded to
// 72 bf16 (2-way bank alias max = free). grid = (N/128, ceil(M/128), S),
// Ksplit = Kfull / S, Ksplit % 64 == 0. No bias/act here (finalize does it).
// ---------------------------------------------------------------------------
union RawT {
  float4 f[8];   // fp32 source: 32 floats
  ushort8 h[8];  // bf16 source: h[0..3] = 32 bf16
};

__device__ inline void load_f32(const float* p, bool valid, RawT& r) {
#pragma unroll
  for (int q = 0; q < 8; ++q)
    r.f[q] = valid ? *(const float4*)(p + q * 4) : make_float4(0.f, 0.f, 0.f, 0.f);
}
__device__ inline void load_b16(const unsigned short* p, bool valid, RawT& r) {
#pragma unroll
  for (int q = 0; q < 4; ++q) {
    if (valid)
      r.h[q] = *(const ushort8*)(p + q * 8);
    else
      r.h[q] = (ushort8)0;
  }
}
__device__ inline void cvt_f32(const RawT& r, ushort8 pk[4]) {
#pragma unroll
  for (int q = 0; q < 4; ++q) {
    float4 a = r.f[2 * q], b = r.f[2 * q + 1];
    __hip_bfloat162 p0 = __float22bfloat162_rn(make_float2(a.x, a.y));
    __hip_bfloat162 p1 = __float22bfloat162_rn(make_float2(a.z, a.w));
    __hip_bfloat162 p2 = __float22bfloat162_rn(make_float2(b.x, b.y));
    __hip_bfloat162 p3 = __float22bfloat162_rn(make_float2(b.z, b.w));
    pk[q][0] = __bfloat16_as_ushort(p0.x);
    pk[q][1] = __bfloat16_as_ushort(p0.y);
    pk[q][2] = __bfloat16_as_ushort(p1.x);
    pk[q][3] = __bfloat16_as_ushort(p1.y);
    pk[q][4] = __bfloat16_as_ushort(p2.x);
    pk[q][5] = __bfloat16_as_ushort(p2.y);
    pk[q][6] = __bfloat16_as_ushort(p3.x);
    pk[q][7] = __bfloat16_as_ushort(p3.y);
  }
}

#define LSTR 72
template <bool ABF16, bool BBF16>
__global__ __launch_bounds__(256) void gemm_mfma(
    const void* __restrict__ Ap, const void* __restrict__ Bp,
    float* __restrict__ Cpart, int M, int N, int Kfull, int Ksplit) {
  __shared__ unsigned short As[128 * LSTR];
  __shared__ unsigned short Bs[128 * LSTR];
  const int tid = threadIdx.x;
  const int m0 = blockIdx.y * 128;
  const int n0 = blockIdx.x * 128;
  const int s = blockIdx.z;
  const int k0 = s * Ksplit;

  const int srow = tid >> 1;          // 0..127
  const int scol = (tid & 1) * 32;    // 0 or 32
  const bool avalid = (m0 + srow) < M;
  const bool bvalid = (n0 + srow) < N;

  const float* Af = (const float*)Ap + (size_t)(m0 + srow) * Kfull + k0 + scol;
  const unsigned short* Ab =
      (const unsigned short*)Ap + (size_t)(m0 + srow) * Kfull + k0 + scol;
  const float* Bf = (const float*)Bp + (size_t)(n0 + srow) * Kfull + k0 + scol;
  const unsigned short* Bb =
      (const unsigned short*)Bp + (size_t)(n0 + srow) * Kfull + k0 + scol;

  const int wave = tid >> 6;
  const int lane = tid & 63;
  const int wm = (wave >> 1) * 64;
  const int wn = (wave & 1) * 64;
  const int fm = lane & 15;
  const int fk = (lane >> 4) * 8;

  f32x4 acc[4][4];
#pragma unroll
  for (int i = 0; i < 4; ++i)
#pragma unroll
    for (int j = 0; j < 4; ++j) acc[i][j] = (f32x4)(0.0f);

  RawT ra, rb;
  if (ABF16) load_b16(Ab, avalid, ra); else load_f32(Af, avalid, ra);
  if (BBF16) load_b16(Bb, bvalid, rb); else load_f32(Bf, bvalid, rb);
  RawT na = ra, nb = rb;

  for (int kt = 0; kt < Ksplit; kt += 64) {
    int ktn = kt + 64;
    if (ktn < Ksplit) {  // prefetch next slab (overlaps MFMA below)
      if (ABF16) load_b16(Ab + ktn, avalid, na); else load_f32(Af + ktn, avalid, na);
      if (BBF16) load_b16(Bb + ktn, bvalid, nb); else load_f32(Bf + ktn, bvalid, nb);
    }
    ushort8 pa[4], pb[4];
    if (ABF16) {
#pragma unroll
      for (int q = 0; q < 4; ++q) pa[q] = ra.h[q];
    } else
      cvt_f32(ra, pa);
    if (BBF16) {
#pragma unroll
      for (int q = 0; q < 4; ++q) pb[q] = rb.h[q];
    } else
      cvt_f32(rb, pb);

    __syncthreads();
    unsigned short* aw = &As[srow * LSTR + scol];
    unsigned short* bw = &Bs[srow * LSTR + scol];
    *(ushort8*)(aw) = pa[0];
    *(ushort8*)(aw + 8) = pa[1];
    *(ushort8*)(aw + 16) = pa[2];
    *(ushort8*)(aw + 24) = pa[3];
    *(ushort8*)(bw) = pb[0];
    *(ushort8*)(bw + 8) = pb[1];
    *(ushort8*)(bw + 16) = pb[2];
    *(ushort8*)(bw + 24) = pb[3];
    __syncthreads();

#pragma unroll
    for (int kk = 0; kk < 64; kk += 32) {
      bf16x8 af[4], bfr[4];
#pragma unroll
      for (int i = 0; i < 4; ++i)
        af[i] = *(const bf16x8*)&As[(wm + i * 16 + fm) * LSTR + kk + fk];
#pragma unroll
      for (int j = 0; j < 4; ++j)
        bfr[j] = *(const bf16x8*)&Bs[(wn + j * 16 + fm) * LSTR + kk + fk];
#pragma unroll
      for (int i = 0; i < 4; ++i)
#pragma unroll
        for (int j = 0; j < 4; ++j)
          acc[i][j] = __builtin_amdgcn_mfma_f32_16x16x32_bf16(af[i], bfr[j],
                                                              acc[i][j], 0, 0, 0);
    }
    ra = na;
    rb = nb;
  }

  // epilogue: C/D layout col=lane&15, row=(lane>>4)*4+r
  const int col = lane & 15;
  const int rb4 = (lane >> 4) * 4;
  float* Cp = Cpart + (size_t)s * M * N;
#pragma unroll
  for (int i = 0; i < 4; ++i) {
#pragma unroll
    for (int r = 0; r < 4; ++r) {
      int gm = m0 + wm + i * 16 + rb4 + r;
      if (gm >= M) continue;
#pragma unroll
      for (int j = 0; j < 4; ++j) {
        int gn = n0 + wn + j * 16 + col;
        if (gn < N) Cp[(size_t)gm * N + gn] = acc[i][j][r];
      }
    }
  }
}

// ---------------------------------------------------------------------------
// finalize: out = act(sum_s part[s] + bias[axis]) ; fp32 or bf16 out
// ---------------------------------------------------------------------------
__global__ __launch_bounds__(256) void finalize_kernel(
    const float* __restrict__ part, const float* __restrict__ bias,
    void* __restrict__ out, int M, int N, int S, int bias_on_n, int relu,
    int out_bf16) {
  int idx = blockIdx.x * blockDim.x + threadIdx.x;
  if (idx >= M * N) return;
  int m = idx / N;
  int n = idx - m * N;
  float v = 0.0f;
  for (int s2 = 0; s2 < S; ++s2) v += part[(size_t)s2 * M * N + idx];
  v += bias[bias_on_n ? n : m];
  if (relu) v = fmaxf(v, 0.0f);
  if (out_bf16)
    ((unsigned short*)out)[idx] = f2bf(v);
  else
    ((float*)out)[idx] = v;
}

// ---------------------------------------------------------------------------
// softmax over 81 classes; rois passthrough
// ---------------------------------------------------------------------------
__global__ __launch_bounds__(128) void softmax81(const float* __restrict__ in,
                                                 float* __restrict__ out) {
  int r = blockIdx.x * blockDim.x + threadIdx.x;
  if (r >= R_ROIS) return;
  const float* x = in + r * NCLS;
  float m = -1e30f;
  for (int i = 0; i < NCLS; ++i) m = fmaxf(m, x[i]);
  float s = 0.0f;
  for (int i = 0; i < NCLS; ++i) s += expf(x[i] - m);
  float inv = 1.0f / s;
  float* o = out + r * NCLS;
  for (int i = 0; i < NCLS; ++i) o[i] = expf(x[i] - m) * inv;
}

__global__ __launch_bounds__(256) void copy_rois(const float* __restrict__ rois,
                                                 float* __restrict__ out) {
  int i = blockIdx.x * blockDim.x + threadIdx.x;
  if (i < R_ROIS * 5) out[i] = rois[i];
}

// ---------------------------------------------------------------------------
// Launch
// ---------------------------------------------------------------------------
extern "C" void kernel_launch(void* const* d_in, const int* in_sizes, int n_in,
                              void* d_out, int out_size, void* d_ws,
                              size_t ws_size, hipStream_t stream) {
  const float* im = (const float*)d_in[0];
  const float* rois = (const float*)d_in[1];
  const float* w1 = (const float*)d_in[2];
  const float* b1 = (const float*)d_in[3];
  const float* w2 = (const float*)d_in[4];
  const float* b2 = (const float*)d_in[5];
  const float* w3 = (const float*)d_in[6];
  const float* b3 = (const float*)d_in[7];
  const float* w4 = (const float*)d_in[8];
  const float* b4 = (const float*)d_in[9];
  const float* fc6_w = (const float*)d_in[10];
  const float* fc6_b = (const float*)d_in[11];
  const float* fc7_w = (const float*)d_in[12];
  const float* fc7_b = (const float*)d_in[13];
  const float* cls_w = (const float*)d_in[14];
  const float* cls_b = (const float*)d_in[15];
  const float* bbox_w = (const float*)d_in[16];
  const float* bbox_b = (const float*)d_in[17];

  float* ws = (float*)d_ws;
  // layout (float offsets), total 24,576,000 floats = 98.3 MB:
  //   x1   @ 0          : 6,553,600   (64x320x320) -- overlaid later by
  //        pooledb @0 (3,763,200), h6b @3,763,200 (614,400),
  //        h7b @4,377,600 (614,400), cls_score @4,992,000 (24,300)
  //   x2   @ 6,553,600  : 3,276,800   (128x160x160)
  //   x3   @ 9,830,400  : 1,638,400   (256x80x80)
  //   x4   @ 11,468,800 :   819,200   (512x40x40)
  //   col  @ 12,288,000 : 7,372,800   (bf16: 14,745,600 ushorts, max conv2)
  //   cpart@ 19,660,800 : 4,915,200   (split-K partials, conv stages + heads)
  //   cpart_fc @ 5,120,000 : 17,203,200 max (fc6 S=14) -- region 5.12M..22.3M
  //        is dead during fc6/fc7 (x2/x3/x4/col all consumed before roi_align
  //        completes; pooledb/h6b/h7b/cls_score end at 5,016,300).
  float* x1 = ws;
  float* x2 = ws + 6553600;
  float* x3 = ws + 9830400;
  float* x4 = ws + 11468800;
  unsigned short* col = (unsigned short*)(ws + 12288000);
  float* cpart = ws + 19660800;
  float* cpart_fc = ws + 5120000;
  unsigned short* pooledb = (unsigned short*)ws;
  unsigned short* h6b = (unsigned short*)(ws + 3763200);
  unsigned short* h7b = (unsigned short*)(ws + 4377600);
  float* cls_score = ws + 4992000;

  float* out = (float*)d_out;
  float* out_rois = out;          // 1500
  float* out_cls = out + 1500;    // 24300
  float* out_bbox = out + 25800;  // 97200

  // conv1: (3,640,640) -> (64,320,320), direct
  conv_s2_relu<3, 4><<<dim3(400, 16), 256, 0, stream>>>(im, w1, b1, x1, 640,
                                                        640, 320, 320);

  // conv2: im2col + GEMM  M=128 N=25600 K=576
  im2col_bf16<<<dim3(6400), 256, 0, stream>>>(x1, col, 64, 320, 320, 160, 160);
  gemm_mfma<false, true><<<dim3(200, 1, 1), 256, 0, stream>>>(
      w2, col, cpart, 128, 25600, 576, 576);
  finalize_kernel<<<dim3(12800), 256, 0, stream>>>(cpart, b2, x2, 128, 25600,
                                                   1, 0, 1, 0);

  // conv3: M=256 N=6400 K=1152, S=2
  im2col_bf16<<<dim3(3200), 256, 0, stream>>>(x2, col, 128, 160, 160, 80, 80);
  gemm_mfma<false, true><<<dim3(50, 2, 2), 256, 0, stream>>>(
      w3, col, cpart, 256, 6400, 1152, 576);
  finalize_kernel<<<dim3(6400), 256, 0, stream>>>(cpart, b3, x3, 256, 6400, 2,
                                                  0, 1, 0);

  // conv4: M=512 N=1600 K=2304, S=4
  im2col_bf16<<<dim3(1600), 256, 0, stream>>>(x3, col, 256, 80, 80, 40, 40);
  gemm_mfma<false, true><<<dim3(13, 4, 4), 256, 0, stream>>>(
      w4, col, cpart, 512, 1600, 2304, 576);
  finalize_kernel<<<dim3(3200), 256, 0, stream>>>(cpart, b4, x4, 512, 1600, 4,
                                                  0, 1, 0);

  // roi align -> bf16 pooled (300 x 25088)
  roi_align_kernel<<<dim3(29400), 256, 0, stream>>>(x4, rois, pooledb);

  // fc6: M=300 N=4096 K=25088, S=14 (Ksplit=1792=28*64) -> h6 (bf16, relu)
  // grid 32*3*14 = 1344 blocks: fills 256 CUs at 4 resident blocks/CU
  // (LDS-capped), vs S=4's 384 blocks = 1.5/CU = latency-bound starvation.
  gemm_mfma<true, false><<<dim3(32, 3, 14), 256, 0, stream>>>(
      pooledb, fc6_w, cpart_fc, 300, 4096, 25088, 1792);
  finalize_kernel<<<dim3(4800), 256, 0, stream>>>(cpart_fc, fc6_b, h6b, 300,
                                                  4096, 14, 1, 1, 1);

  // fc7: M=300 N=4096 K=4096, S=8 (Ksplit=512) -> h7 (bf16, relu)
  gemm_mfma<true, false><<<dim3(32, 3, 8), 256, 0, stream>>>(
      h6b, fc7_w, cpart_fc, 300, 4096, 4096, 512);
  finalize_kernel<<<dim3(4800), 256, 0, stream>>>(cpart_fc, fc7_b, h7b, 300,
                                                  4096, 8, 1, 1, 1);

  // cls head: M=300 N=81 K=4096, S=16 -> cls_score (fp32)
  gemm_mfma<true, false><<<dim3(1, 3, 16), 256, 0, stream>>>(
      h7b, cls_w, cpart, 300, 81, 4096, 256);
  finalize_kernel<<<dim3(95), 256, 0, stream>>>(cpart, cls_b, cls_score, 300,
                                                81, 16, 1, 0, 0);

  // bbox head: M=300 N=324 K=4096, S=16 -> out_bbox (fp32)
  gemm_mfma<true, false><<<dim3(3, 3, 16), 256, 0, stream>>>(
      h7b, bbox_w, cpart, 300, 324, 4096, 256);
  finalize_kernel<<<dim3(380), 256, 0, stream>>>(cpart, bbox_b, out_bbox, 300,
                                                 324, 16, 1, 0, 0);

  softmax81<<<dim3(3), 128, 0, stream>>>(cls_score, out_cls);
  copy_rois<<<dim3(6), 256, 0, stream>>>(rois, out_rois);
}

// Round 3
// 1165.174 us; speedup vs baseline: 1.1449x; 1.1206x over previous
//
#include <hip/hip_runtime.h>
#include <hip/hip_bf16.h>
#include <math.h>

#define R_ROIS 300
#define NCLS 81
#define RCNN_DIN 4096
#define K_FC6 25088
#define FEAT_H 40
#define FEAT_W 40

typedef __attribute__((ext_vector_type(8))) short bf16x8;
typedef __attribute__((ext_vector_type(4))) float f32x4;
typedef __attribute__((ext_vector_type(8))) unsigned short ushort8;
typedef __attribute__((ext_vector_type(4))) unsigned short u16x4;

__device__ inline unsigned short f2bf(float x) {
  union { float f; unsigned u; } v;
  v.f = x;
  unsigned r = v.u + 0x7fff + ((v.u >> 16) & 1);  // RNE
  return (unsigned short)(r >> 16);
}

// ---------------------------------------------------------------------------
// conv1 direct (tiny CIN=3): stride-2 3x3, SAME, bias+relu
// ---------------------------------------------------------------------------
template <int CIN, int COPT>
__global__ __launch_bounds__(256) void conv_s2_relu(
    const float* __restrict__ in, const float* __restrict__ w,
    const float* __restrict__ bias, float* __restrict__ out,
    int Hin, int Win, int Hout, int Wout) {
  int pix = blockIdx.x * blockDim.x + threadIdx.x;
  int npix = Hout * Wout;
  if (pix >= npix) return;
  int co0 = blockIdx.y * COPT;
  int oy = pix / Wout, ox = pix % Wout;

  float acc[COPT];
#pragma unroll
  for (int j = 0; j < COPT; ++j) acc[j] = bias[co0 + j];

  for (int cin = 0; cin < CIN; ++cin) {
    const float* ip = in + cin * Hin * Win;
    const float* wp = w + (co0 * CIN + cin) * 9;
#pragma unroll
    for (int ky = 0; ky < 3; ++ky) {
      int iy = oy * 2 + ky;
      if (iy >= Hin) continue;
#pragma unroll
      for (int kx = 0; kx < 3; ++kx) {
        int ix = ox * 2 + kx;
        if (ix >= Win) continue;
        float v = ip[iy * Win + ix];
#pragma unroll
        for (int j = 0; j < COPT; ++j)
          acc[j] = fmaf(v, wp[j * CIN * 9 + ky * 3 + kx], acc[j]);
      }
    }
  }
#pragma unroll
  for (int j = 0; j < COPT; ++j)
    out[(co0 + j) * npix + pix] = fmaxf(acc[j], 0.0f);
}

// ---------------------------------------------------------------------------
// im2col (stride-2 3x3 SAME), fp32 in -> bf16 col[pix][cin*9+q]
// ---------------------------------------------------------------------------
__global__ __launch_bounds__(256) void im2col_bf16(
    const float* __restrict__ in, unsigned short* __restrict__ col,
    int Cin, int Hin, int Win, int Hout, int Wout) {
  int idx = blockIdx.x * blockDim.x + threadIdx.x;
  int npix = Hout * Wout;
  if (idx >= npix * Cin) return;
  int pix = idx % npix;  // consecutive threads -> consecutive ox (read coalesce)
  int cin = idx / npix;
  int oy = pix / Wout, ox = pix % Wout;
  const float* ip = in + (size_t)cin * Hin * Win;
  unsigned short* cp = col + (size_t)pix * (Cin * 9) + cin * 9;
#pragma unroll
  for (int ky = 0; ky < 3; ++ky) {
    int iy = oy * 2 + ky;
#pragma unroll
    for (int kx = 0; kx < 3; ++kx) {
      int ix = ox * 2 + kx;
      float v = (iy < Hin && ix < Win) ? ip[iy * Win + ix] : 0.0f;
      cp[ky * 3 + kx] = f2bf(v);
    }
  }
}

// ---------------------------------------------------------------------------
// ROI align -> bf16 pooled (300, 512*7*7)
// ---------------------------------------------------------------------------
__global__ __launch_bounds__(256) void roi_align_kernel(
    const float* __restrict__ feat, const float* __restrict__ rois,
    unsigned short* __restrict__ out) {
  int idx = blockIdx.x * blockDim.x + threadIdx.x;
  if (idx >= R_ROIS * 512 * 49) return;
  int pw = idx % 7;
  int t = idx / 7;
  int ph = t % 7;
  t /= 7;
  int c = t % 512;
  int r = t / 512;

  const float SCALE = 1.0f / 16.0f;
  float x1 = rois[r * 5 + 1] * SCALE;
  float y1 = rois[r * 5 + 2] * SCALE;
  float x2 = rois[r * 5 + 3] * SCALE;
  float y2 = rois[r * 5 + 4] * SCALE;
  float bw = fmaxf(x2 - x1, 1.0f) * (1.0f / 7.0f);
  float bh = fmaxf(y2 - y1, 1.0f) * (1.0f / 7.0f);

  const float* f = feat + c * FEAT_H * FEAT_W;
  float s = 0.0f;
#pragma unroll
  for (int sy = 0; sy < 2; ++sy) {
    float gy = y1 + ((float)(ph * 2 + sy) + 0.5f) * 0.5f * bh;
    gy = fminf(fmaxf(gy, 0.0f), (float)(FEAT_H - 1));
    int y0 = (int)floorf(gy);
    float wy = gy - (float)y0;
    int y1i = min(y0 + 1, FEAT_H - 1);
#pragma unroll
    for (int sx = 0; sx < 2; ++sx) {
      float gx = x1 + ((float)(pw * 2 + sx) + 0.5f) * 0.5f * bw;
      gx = fminf(fmaxf(gx, 0.0f), (float)(FEAT_W - 1));
      int x0 = (int)floorf(gx);
      float wx = gx - (float)x0;
      int x1i = min(x0 + 1, FEAT_W - 1);
      float v00 = f[y0 * FEAT_W + x0];
      float v01 = f[y0 * FEAT_W + x1i];
      float v10 = f[y1i * FEAT_W + x0];
      float v11 = f[y1i * FEAT_W + x1i];
      s += v00 * (1.0f - wy) * (1.0f - wx) + v01 * (1.0f - wy) * wx +
           v10 * wy * (1.0f - wx) + v11 * wy * wx;
    }
  }
  out[idx] = f2bf(s * 0.25f);
}

// ---------------------------------------------------------------------------
// Generic MFMA GEMM: Cpart[s] (M,N) = A(M,K) @ B(N,K)^T over k-range s.
// A/B fp32 or bf16 in HBM; LDS bf16; 128x128 tile, BK=64, 256 thr (4 waves,
// wave tile 64x64 = 4x4 of 16x16x32). Register double-buffer prefetch of the
// next K-slab overlaps global latency with the MFMA loop.
//
// Staging mapping: WAVE-CONTIGUOUS global reads.
//   fp32 src: thread t reads rows r=q*16+(t>>4), floats (t&15)*4.. (+3), q=0..7
//     -> one wave instr = 4 rows x 256B contiguous (8 cache lines, was 64).
//   bf16 src: thread t reads rows r=q*32+(t>>3), bf16 (t&7)*8.. (+7), q=0..3
//     -> one wave instr = 8 rows x 128B contiguous (8 cache lines, was 64).
// LDS tile layout/frag reads unchanged (rows padded to 72 bf16).
// grid = (N/128, ceil(M/128), S), Ksplit = Kfull/S, Ksplit % 64 == 0.
// ---------------------------------------------------------------------------
union RawT {
  float4 f[8];   // fp32 source: 32 floats (8 rows x 4)
  ushort8 h[8];  // bf16 source: h[0..3] = 32 bf16 (4 rows x 8)
};

__device__ inline void load_f32c(const float* p, size_t K, int row0, int Lim,
                                 RawT& r) {
#pragma unroll
  for (int q = 0; q < 8; ++q) {
    const float4* src = (const float4*)(p + (size_t)(q * 16) * K);
    r.f[q] = (row0 + q * 16 < Lim) ? *src : make_float4(0.f, 0.f, 0.f, 0.f);
  }
}
__device__ inline void load_b16c(const unsigned short* p, size_t K, int row0,
                                 int Lim, RawT& r) {
#pragma unroll
  for (int q = 0; q < 4; ++q) {
    const ushort8* src = (const ushort8*)(p + (size_t)(q * 32) * K);
    r.h[q] = (row0 + q * 32 < Lim) ? *src : (ushort8)0;
  }
}
__device__ inline u16x4 cvt4(float4 a) {
  __hip_bfloat162 p0 = __float22bfloat162_rn(make_float2(a.x, a.y));
  __hip_bfloat162 p1 = __float22bfloat162_rn(make_float2(a.z, a.w));
  u16x4 o;
  o[0] = __bfloat16_as_ushort(p0.x);
  o[1] = __bfloat16_as_ushort(p0.y);
  o[2] = __bfloat16_as_ushort(p1.x);
  o[3] = __bfloat16_as_ushort(p1.y);
  return o;
}

#define LSTR 72
template <bool ABF16, bool BBF16>
__global__ __launch_bounds__(256) void gemm_mfma(
    const void* __restrict__ Ap, const void* __restrict__ Bp,
    float* __restrict__ Cpart, int M, int N, int Kfull, int Ksplit) {
  __shared__ unsigned short As[128 * LSTR];
  __shared__ unsigned short Bs[128 * LSTR];
  const int tid = threadIdx.x;
  const int m0 = blockIdx.y * 128;
  const int n0 = blockIdx.x * 128;
  const int s = blockIdx.z;
  const int k0 = s * Ksplit;

  const int fr32 = tid >> 4;        // fp32 staging: row within 16-row group
  const int fc32 = (tid & 15) * 4;  // float col within 64-slab
  const int fr16 = tid >> 3;        // bf16 staging: row within 32-row group
  const int fc16 = (tid & 7) * 8;   // bf16 col within 64-slab

  const int ar0 = m0 + (ABF16 ? fr16 : fr32);
  const int br0 = n0 + (BBF16 ? fr16 : fr32);

  const float* Af = (const float*)Ap + (size_t)ar0 * Kfull + k0 + fc32;
  const unsigned short* Ab =
      (const unsigned short*)Ap + (size_t)ar0 * Kfull + k0 + fc16;
  const float* Bf = (const float*)Bp + (size_t)br0 * Kfull + k0 + fc32;
  const unsigned short* Bb =
      (const unsigned short*)Bp + (size_t)br0 * Kfull + k0 + fc16;

  const int wave = tid >> 6;
  const int lane = tid & 63;
  const int wm = (wave >> 1) * 64;
  const int wn = (wave & 1) * 64;
  const int fm = lane & 15;
  const int fk = (lane >> 4) * 8;

  f32x4 acc[4][4];
#pragma unroll
  for (int i = 0; i < 4; ++i)
#pragma unroll
    for (int j = 0; j < 4; ++j) acc[i][j] = (f32x4)(0.0f);

  RawT ra, rb;
  if (ABF16) load_b16c(Ab, Kfull, ar0, M, ra); else load_f32c(Af, Kfull, ar0, M, ra);
  if (BBF16) load_b16c(Bb, Kfull, br0, N, rb); else load_f32c(Bf, Kfull, br0, N, rb);
  RawT na = ra, nb = rb;

  for (int kt = 0; kt < Ksplit; kt += 64) {
    int ktn = kt + 64;
    if (ktn < Ksplit) {  // prefetch next slab (overlaps MFMA below)
      if (ABF16) load_b16c(Ab + ktn, Kfull, ar0, M, na);
      else       load_f32c(Af + ktn, Kfull, ar0, M, na);
      if (BBF16) load_b16c(Bb + ktn, Kfull, br0, N, nb);
      else       load_f32c(Bf + ktn, Kfull, br0, N, nb);
    }

    __syncthreads();
    if (ABF16) {
#pragma unroll
      for (int q = 0; q < 4; ++q)
        *(ushort8*)&As[(fr16 + q * 32) * LSTR + fc16] = ra.h[q];
    } else {
#pragma unroll
      for (int q = 0; q < 8; ++q)
        *(u16x4*)&As[(fr32 + q * 16) * LSTR + fc32] = cvt4(ra.f[q]);
    }
    if (BBF16) {
#pragma unroll
      for (int q = 0; q < 4; ++q)
        *(ushort8*)&Bs[(fr16 + q * 32) * LSTR + fc16] = rb.h[q];
    } else {
#pragma unroll
      for (int q = 0; q < 8; ++q)
        *(u16x4*)&Bs[(fr32 + q * 16) * LSTR + fc32] = cvt4(rb.f[q]);
    }
    __syncthreads();

#pragma unroll
    for (int kk = 0; kk < 64; kk += 32) {
      bf16x8 af[4], bfr[4];
#pragma unroll
      for (int i = 0; i < 4; ++i)
        af[i] = *(const bf16x8*)&As[(wm + i * 16 + fm) * LSTR + kk + fk];
#pragma unroll
      for (int j = 0; j < 4; ++j)
        bfr[j] = *(const bf16x8*)&Bs[(wn + j * 16 + fm) * LSTR + kk + fk];
#pragma unroll
      for (int i = 0; i < 4; ++i)
#pragma unroll
        for (int j = 0; j < 4; ++j)
          acc[i][j] = __builtin_amdgcn_mfma_f32_16x16x32_bf16(af[i], bfr[j],
                                                              acc[i][j], 0, 0, 0);
    }
    ra = na;
    rb = nb;
  }

  // epilogue: C/D layout col=lane&15, row=(lane>>4)*4+r
  const int col = lane & 15;
  const int rb4 = (lane >> 4) * 4;
  float* Cp = Cpart + (size_t)s * M * N;
#pragma unroll
  for (int i = 0; i < 4; ++i) {
#pragma unroll
    for (int r = 0; r < 4; ++r) {
      int gm = m0 + wm + i * 16 + rb4 + r;
      if (gm >= M) continue;
#pragma unroll
      for (int j = 0; j < 4; ++j) {
        int gn = n0 + wn + j * 16 + col;
        if (gn < N) Cp[(size_t)gm * N + gn] = acc[i][j][r];
      }
    }
  }
}

// ---------------------------------------------------------------------------
// finalize: out = act(sum_s part[s] + bias[axis]) ; fp32 or bf16 out
// ---------------------------------------------------------------------------
__global__ __launch_bounds__(256) void finalize_kernel(
    const float* __restrict__ part, const float* __restrict__ bias,
    void* __restrict__ out, int M, int N, int S, int bias_on_n, int relu,
    int out_bf16) {
  int idx = blockIdx.x * blockDim.x + threadIdx.x;
  if (idx >= M * N) return;
  int m = idx / N;
  int n = idx - m * N;
  float v = 0.0f;
  for (int s2 = 0; s2 < S; ++s2) v += part[(size_t)s2 * M * N + idx];
  v += bias[bias_on_n ? n : m];
  if (relu) v = fmaxf(v, 0.0f);
  if (out_bf16)
    ((unsigned short*)out)[idx] = f2bf(v);
  else
    ((float*)out)[idx] = v;
}

// ---------------------------------------------------------------------------
// softmax over 81 classes; rois passthrough
// ---------------------------------------------------------------------------
__global__ __launch_bounds__(128) void softmax81(const float* __restrict__ in,
                                                 float* __restrict__ out) {
  int r = blockIdx.x * blockDim.x + threadIdx.x;
  if (r >= R_ROIS) return;
  const float* x = in + r * NCLS;
  float m = -1e30f;
  for (int i = 0; i < NCLS; ++i) m = fmaxf(m, x[i]);
  float s = 0.0f;
  for (int i = 0; i < NCLS; ++i) s += expf(x[i] - m);
  float inv = 1.0f / s;
  float* o = out + r * NCLS;
  for (int i = 0; i < NCLS; ++i) o[i] = expf(x[i] - m) * inv;
}

__global__ __launch_bounds__(256) void copy_rois(const float* __restrict__ rois,
                                                 float* __restrict__ out) {
  int i = blockIdx.x * blockDim.x + threadIdx.x;
  if (i < R_ROIS * 5) out[i] = rois[i];
}

// ---------------------------------------------------------------------------
// Launch
// ---------------------------------------------------------------------------
extern "C" void kernel_launch(void* const* d_in, const int* in_sizes, int n_in,
                              void* d_out, int out_size, void* d_ws,
                              size_t ws_size, hipStream_t stream) {
  const float* im = (const float*)d_in[0];
  const float* rois = (const float*)d_in[1];
  const float* w1 = (const float*)d_in[2];
  const float* b1 = (const float*)d_in[3];
  const float* w2 = (const float*)d_in[4];
  const float* b2 = (const float*)d_in[5];
  const float* w3 = (const float*)d_in[6];
  const float* b3 = (const float*)d_in[7];
  const float* w4 = (const float*)d_in[8];
  const float* b4 = (const float*)d_in[9];
  const float* fc6_w = (const float*)d_in[10];
  const float* fc6_b = (const float*)d_in[11];
  const float* fc7_w = (const float*)d_in[12];
  const float* fc7_b = (const float*)d_in[13];
  const float* cls_w = (const float*)d_in[14];
  const float* cls_b = (const float*)d_in[15];
  const float* bbox_w = (const float*)d_in[16];
  const float* bbox_b = (const float*)d_in[17];

  float* ws = (float*)d_ws;
  // layout (float offsets), total 24,576,000 floats = 98.3 MB:
  //   x1   @ 0          : 6,553,600   (64x320x320) -- overlaid later by
  //        pooledb @0 (3,763,200), h6b @3,763,200 (614,400),
  //        h7b @4,377,600 (614,400), cls_score @4,992,000 (24,300)
  //   x2   @ 6,553,600  : 3,276,800   (128x160x160)
  //   x3   @ 9,830,400  : 1,638,400   (256x80x80)
  //   x4   @ 11,468,800 :   819,200   (512x40x40)
  //   col  @ 12,288,000 : 7,372,800   (bf16: 14,745,600 ushorts, max conv2)
  //   cpart@ 19,660,800 : 4,915,200   (split-K partials, conv stages + heads)
  //   cpart_fc @ 5,120,000 : 17,203,200 max (fc6 S=14) -- region 5.12M..22.3M
  //        is dead during fc6/fc7 (x2/x3/x4/col all consumed before roi_align
  //        completes; pooledb/h6b/h7b/cls_score end at 5,016,300).
  float* x1 = ws;
  float* x2 = ws + 6553600;
  float* x3 = ws + 9830400;
  float* x4 = ws + 11468800;
  unsigned short* col = (unsigned short*)(ws + 12288000);
  float* cpart = ws + 19660800;
  float* cpart_fc = ws + 5120000;
  unsigned short* pooledb = (unsigned short*)ws;
  unsigned short* h6b = (unsigned short*)(ws + 3763200);
  unsigned short* h7b = (unsigned short*)(ws + 4377600);
  float* cls_score = ws + 4992000;

  float* out = (float*)d_out;
  float* out_rois = out;          // 1500
  float* out_cls = out + 1500;    // 24300
  float* out_bbox = out + 25800;  // 97200

  // conv1: (3,640,640) -> (64,320,320), direct
  conv_s2_relu<3, 4><<<dim3(400, 16), 256, 0, stream>>>(im, w1, b1, x1, 640,
                                                        640, 320, 320);

  // conv2: im2col + GEMM  M=128 N=25600 K=576
  im2col_bf16<<<dim3(6400), 256, 0, stream>>>(x1, col, 64, 320, 320, 160, 160);
  gemm_mfma<false, true><<<dim3(200, 1, 1), 256, 0, stream>>>(
      w2, col, cpart, 128, 25600, 576, 576);
  finalize_kernel<<<dim3(12800), 256, 0, stream>>>(cpart, b2, x2, 128, 25600,
                                                   1, 0, 1, 0);

  // conv3: M=256 N=6400 K=1152, S=2
  im2col_bf16<<<dim3(3200), 256, 0, stream>>>(x2, col, 128, 160, 160, 80, 80);
  gemm_mfma<false, true><<<dim3(50, 2, 2), 256, 0, stream>>>(
      w3, col, cpart, 256, 6400, 1152, 576);
  finalize_kernel<<<dim3(6400), 256, 0, stream>>>(cpart, b3, x3, 256, 6400, 2,
                                                  0, 1, 0);

  // conv4: M=512 N=1600 K=2304, S=4
  im2col_bf16<<<dim3(1600), 256, 0, stream>>>(x3, col, 256, 80, 80, 40, 40);
  gemm_mfma<false, true><<<dim3(13, 4, 4), 256, 0, stream>>>(
      w4, col, cpart, 512, 1600, 2304, 576);
  finalize_kernel<<<dim3(3200), 256, 0, stream>>>(cpart, b4, x4, 512, 1600, 4,
                                                  0, 1, 0);

  // roi align -> bf16 pooled (300 x 25088)
  roi_align_kernel<<<dim3(29400), 256, 0, stream>>>(x4, rois, pooledb);

  // fc6: M=300 N=4096 K=25088, S=14 (Ksplit=1792=28*64) -> h6 (bf16, relu)
  gemm_mfma<true, false><<<dim3(32, 3, 14), 256, 0, stream>>>(
      pooledb, fc6_w, cpart_fc, 300, 4096, 25088, 1792);
  finalize_kernel<<<dim3(4800), 256, 0, stream>>>(cpart_fc, fc6_b, h6b, 300,
                                                  4096, 14, 1, 1, 1);

  // fc7: M=300 N=4096 K=4096, S=8 (Ksplit=512) -> h7 (bf16, relu)
  gemm_mfma<true, false><<<dim3(32, 3, 8), 256, 0, stream>>>(
      h6b, fc7_w, cpart_fc, 300, 4096, 4096, 512);
  finalize_kernel<<<dim3(4800), 256, 0, stream>>>(cpart_fc, fc7_b, h7b, 300,
                                                  4096, 8, 1, 1, 1);

  // cls head: M=300 N=81 K=4096, S=16 -> cls_score (fp32)
  gemm_mfma<true, false><<<dim3(1, 3, 16), 256, 0, stream>>>(
      h7b, cls_w, cpart, 300, 81, 4096, 256);
  finalize_kernel<<<dim3(95), 256, 0, stream>>>(cpart, cls_b, cls_score, 300,
                                                81, 16, 1, 0, 0);

  // bbox head: M=300 N=324 K=4096, S=16 -> out_bbox (fp32)
  gemm_mfma<true, false><<<dim3(3, 3, 16), 256, 0, stream>>>(
      h7b, bbox_w, cpart, 300, 324, 4096, 256);
  finalize_kernel<<<dim3(380), 256, 0, stream>>>(cpart, bbox_b, out_bbox, 300,
                                                 324, 16, 1, 0, 0);

  softmax81<<<dim3(3), 128, 0, stream>>>(cls_score, out_cls);
  copy_rois<<<dim3(6), 256, 0, stream>>>(rois, out_rois);
}

// Round 4
// 1018.166 us; speedup vs baseline: 1.3102x; 1.1444x over previous
//
#include <hip/hip_runtime.h>
#include <hip/hip_bf16.h>
#include <math.h>

#define R_ROIS 300
#define NCLS 81
#define RCNN_DIN 4096
#define K_FC6 25088
#define FEAT_H 40
#define FEAT_W 40

typedef __attribute__((ext_vector_type(8))) short bf16x8;
typedef __attribute__((ext_vector_type(4))) float f32x4;
typedef __attribute__((ext_vector_type(8))) unsigned short ushort8;
typedef __attribute__((ext_vector_type(4))) unsigned short u16x4;

__device__ inline unsigned short f2bf(float x) {
  union { float f; unsigned u; } v;
  v.f = x;
  unsigned r = v.u + 0x7fff + ((v.u >> 16) & 1);  // RNE
  return (unsigned short)(r >> 16);
}

// ---------------------------------------------------------------------------
// conv1 direct (tiny CIN=3): stride-2 3x3, SAME, bias+relu
// ---------------------------------------------------------------------------
template <int CIN, int COPT>
__global__ __launch_bounds__(256) void conv_s2_relu(
    const float* __restrict__ in, const float* __restrict__ w,
    const float* __restrict__ bias, float* __restrict__ out,
    int Hin, int Win, int Hout, int Wout) {
  int pix = blockIdx.x * blockDim.x + threadIdx.x;
  int npix = Hout * Wout;
  if (pix >= npix) return;
  int co0 = blockIdx.y * COPT;
  int oy = pix / Wout, ox = pix % Wout;

  float acc[COPT];
#pragma unroll
  for (int j = 0; j < COPT; ++j) acc[j] = bias[co0 + j];

  for (int cin = 0; cin < CIN; ++cin) {
    const float* ip = in + cin * Hin * Win;
    const float* wp = w + (co0 * CIN + cin) * 9;
#pragma unroll
    for (int ky = 0; ky < 3; ++ky) {
      int iy = oy * 2 + ky;
      if (iy >= Hin) continue;
#pragma unroll
      for (int kx = 0; kx < 3; ++kx) {
        int ix = ox * 2 + kx;
        if (ix >= Win) continue;
        float v = ip[iy * Win + ix];
#pragma unroll
        for (int j = 0; j < COPT; ++j)
          acc[j] = fmaf(v, wp[j * CIN * 9 + ky * 3 + kx], acc[j]);
      }
    }
  }
#pragma unroll
  for (int j = 0; j < COPT; ++j)
    out[(co0 + j) * npix + pix] = fmaxf(acc[j], 0.0f);
}

// ---------------------------------------------------------------------------
// im2col (stride-2 3x3 SAME), fp32 in -> bf16 col[pix][cin*9+q]
// LDS-staged: block = 32 consecutive pixels x 64 cins.
//   Phase 1: threads (pl=t&31, cl=t>>5) gather stride-2 input (coalesced-ish
//            reads), scatter bf16 into LDS rows (stride 580 ushorts -> bank
//            stride 2, ~2-way = free).
//   Phase 2: flat copy 32x(64*9) ushorts to global as u16x4; consecutive
//            threads -> consecutive 8B chunks within a row => wave-contiguous
//            512B stores, full cache-line coverage (old version: 64-line
//            scatter of 2B chunks per store, ~32x write amplification).
// Requires npix % 32 == 0 and Cin % 64 == 0 (true for all call sites).
// ---------------------------------------------------------------------------
#define I2C_LSTR 580  // 64*9 + 4 pad
__global__ __launch_bounds__(256) void im2col_bf16_staged(
    const float* __restrict__ in, unsigned short* __restrict__ col,
    int Cin, int Hin, int Win, int Hout, int Wout) {
  __shared__ unsigned short lds[32 * I2C_LSTR];
  const int t = threadIdx.x;
  const int pix0 = blockIdx.x * 32;
  const int cin0 = blockIdx.y * 64;

  // phase 1: gather -> LDS
  {
    const int pl = t & 31;   // pixel lane
    const int cl = t >> 5;   // 0..7 cin group
    const int pix = pix0 + pl;
    const int oy = pix / Wout, ox = pix % Wout;
    for (int cc = cl; cc < 64; cc += 8) {
      const float* ip = in + (size_t)(cin0 + cc) * Hin * Win;
      unsigned short* lp = &lds[pl * I2C_LSTR + cc * 9];
#pragma unroll
      for (int ky = 0; ky < 3; ++ky) {
        int iy = oy * 2 + ky;
#pragma unroll
        for (int kx = 0; kx < 3; ++kx) {
          int ix = ox * 2 + kx;
          float v = (iy < Hin && ix < Win) ? ip[iy * Win + ix] : 0.0f;
          lp[ky * 3 + kx] = f2bf(v);
        }
      }
    }
  }
  __syncthreads();

  // phase 2: LDS -> global, wave-contiguous u16x4 stores.
  // 32 rows x 144 u16x4-chunks = 4608 chunks; 18 iters of 256 threads.
  const size_t rowstride = (size_t)Cin * 9;  // ushorts
#pragma unroll
  for (int it = 0; it < 18; ++it) {
    int ch = it * 256 + t;
    int row = ch / 144;
    int pos = ch - row * 144;
    u16x4 v = *(const u16x4*)&lds[row * I2C_LSTR + pos * 4];
    *(u16x4*)(col + (size_t)(pix0 + row) * rowstride + cin0 * 9 + pos * 4) = v;
  }
}

// ---------------------------------------------------------------------------
// ROI align -> bf16 pooled (300, 512*7*7)
// ---------------------------------------------------------------------------
__global__ __launch_bounds__(256) void roi_align_kernel(
    const float* __restrict__ feat, const float* __restrict__ rois,
    unsigned short* __restrict__ out) {
  int idx = blockIdx.x * blockDim.x + threadIdx.x;
  if (idx >= R_ROIS * 512 * 49) return;
  int pw = idx % 7;
  int t = idx / 7;
  int ph = t % 7;
  t /= 7;
  int c = t % 512;
  int r = t / 512;

  const float SCALE = 1.0f / 16.0f;
  float x1 = rois[r * 5 + 1] * SCALE;
  float y1 = rois[r * 5 + 2] * SCALE;
  float x2 = rois[r * 5 + 3] * SCALE;
  float y2 = rois[r * 5 + 4] * SCALE;
  float bw = fmaxf(x2 - x1, 1.0f) * (1.0f / 7.0f);
  float bh = fmaxf(y2 - y1, 1.0f) * (1.0f / 7.0f);

  const float* f = feat + c * FEAT_H * FEAT_W;
  float s = 0.0f;
#pragma unroll
  for (int sy = 0; sy < 2; ++sy) {
    float gy = y1 + ((float)(ph * 2 + sy) + 0.5f) * 0.5f * bh;
    gy = fminf(fmaxf(gy, 0.0f), (float)(FEAT_H - 1));
    int y0 = (int)floorf(gy);
    float wy = gy - (float)y0;
    int y1i = min(y0 + 1, FEAT_H - 1);
#pragma unroll
    for (int sx = 0; sx < 2; ++sx) {
      float gx = x1 + ((float)(pw * 2 + sx) + 0.5f) * 0.5f * bw;
      gx = fminf(fmaxf(gx, 0.0f), (float)(FEAT_W - 1));
      int x0 = (int)floorf(gx);
      float wx = gx - (float)x0;
      int x1i = min(x0 + 1, FEAT_W - 1);
      float v00 = f[y0 * FEAT_W + x0];
      float v01 = f[y0 * FEAT_W + x1i];
      float v10 = f[y1i * FEAT_W + x0];
      float v11 = f[y1i * FEAT_W + x1i];
      s += v00 * (1.0f - wy) * (1.0f - wx) + v01 * (1.0f - wy) * wx +
           v10 * wy * (1.0f - wx) + v11 * wy * wx;
    }
  }
  out[idx] = f2bf(s * 0.25f);
}

// ---------------------------------------------------------------------------
// Generic MFMA GEMM: Cpart[s] (M,N) = A(M,K) @ B(N,K)^T over k-range s.
// A/B fp32 or bf16 in HBM; LDS bf16; 128x128 tile, BK=64, 256 thr (4 waves,
// wave tile 64x64 = 4x4 of 16x16x32). Register double-buffer prefetch of the
// next K-slab overlaps global latency with the MFMA loop.
// Staging mapping: WAVE-CONTIGUOUS global reads.
// ---------------------------------------------------------------------------
union RawT {
  float4 f[8];   // fp32 source: 32 floats (8 rows x 4)
  ushort8 h[8];  // bf16 source: h[0..3] = 32 bf16 (4 rows x 8)
};

__device__ inline void load_f32c(const float* p, size_t K, int row0, int Lim,
                                 RawT& r) {
#pragma unroll
  for (int q = 0; q < 8; ++q) {
    const float4* src = (const float4*)(p + (size_t)(q * 16) * K);
    r.f[q] = (row0 + q * 16 < Lim) ? *src : make_float4(0.f, 0.f, 0.f, 0.f);
  }
}
__device__ inline void load_b16c(const unsigned short* p, size_t K, int row0,
                                 int Lim, RawT& r) {
#pragma unroll
  for (int q = 0; q < 4; ++q) {
    const ushort8* src = (const ushort8*)(p + (size_t)(q * 32) * K);
    r.h[q] = (row0 + q * 32 < Lim) ? *src : (ushort8)0;
  }
}
__device__ inline u16x4 cvt4(float4 a) {
  __hip_bfloat162 p0 = __float22bfloat162_rn(make_float2(a.x, a.y));
  __hip_bfloat162 p1 = __float22bfloat162_rn(make_float2(a.z, a.w));
  u16x4 o;
  o[0] = __bfloat16_as_ushort(p0.x);
  o[1] = __bfloat16_as_ushort(p0.y);
  o[2] = __bfloat16_as_ushort(p1.x);
  o[3] = __bfloat16_as_ushort(p1.y);
  return o;
}

#define LSTR 72
template <bool ABF16, bool BBF16>
__global__ __launch_bounds__(256) void gemm_mfma(
    const void* __restrict__ Ap, const void* __restrict__ Bp,
    float* __restrict__ Cpart, int M, int N, int Kfull, int Ksplit) {
  __shared__ unsigned short As[128 * LSTR];
  __shared__ unsigned short Bs[128 * LSTR];
  const int tid = threadIdx.x;
  const int m0 = blockIdx.y * 128;
  const int n0 = blockIdx.x * 128;
  const int s = blockIdx.z;
  const int k0 = s * Ksplit;

  const int fr32 = tid >> 4;        // fp32 staging: row within 16-row group
  const int fc32 = (tid & 15) * 4;  // float col within 64-slab
  const int fr16 = tid >> 3;        // bf16 staging: row within 32-row group
  const int fc16 = (tid & 7) * 8;   // bf16 col within 64-slab

  const int ar0 = m0 + (ABF16 ? fr16 : fr32);
  const int br0 = n0 + (BBF16 ? fr16 : fr32);

  const float* Af = (const float*)Ap + (size_t)ar0 * Kfull + k0 + fc32;
  const unsigned short* Ab =
      (const unsigned short*)Ap + (size_t)ar0 * Kfull + k0 + fc16;
  const float* Bf = (const float*)Bp + (size_t)br0 * Kfull + k0 + fc32;
  const unsigned short* Bb =
      (const unsigned short*)Bp + (size_t)br0 * Kfull + k0 + fc16;

  const int wave = tid >> 6;
  const int lane = tid & 63;
  const int wm = (wave >> 1) * 64;
  const int wn = (wave & 1) * 64;
  const int fm = lane & 15;
  const int fk = (lane >> 4) * 8;

  f32x4 acc[4][4];
#pragma unroll
  for (int i = 0; i < 4; ++i)
#pragma unroll
    for (int j = 0; j < 4; ++j) acc[i][j] = (f32x4)(0.0f);

  RawT ra, rb;
  if (ABF16) load_b16c(Ab, Kfull, ar0, M, ra); else load_f32c(Af, Kfull, ar0, M, ra);
  if (BBF16) load_b16c(Bb, Kfull, br0, N, rb); else load_f32c(Bf, Kfull, br0, N, rb);
  RawT na = ra, nb = rb;

  for (int kt = 0; kt < Ksplit; kt += 64) {
    int ktn = kt + 64;
    if (ktn < Ksplit) {  // prefetch next slab (overlaps MFMA below)
      if (ABF16) load_b16c(Ab + ktn, Kfull, ar0, M, na);
      else       load_f32c(Af + ktn, Kfull, ar0, M, na);
      if (BBF16) load_b16c(Bb + ktn, Kfull, br0, N, nb);
      else       load_f32c(Bf + ktn, Kfull, br0, N, nb);
    }

    __syncthreads();
    if (ABF16) {
#pragma unroll
      for (int q = 0; q < 4; ++q)
        *(ushort8*)&As[(fr16 + q * 32) * LSTR + fc16] = ra.h[q];
    } else {
#pragma unroll
      for (int q = 0; q < 8; ++q)
        *(u16x4*)&As[(fr32 + q * 16) * LSTR + fc32] = cvt4(ra.f[q]);
    }
    if (BBF16) {
#pragma unroll
      for (int q = 0; q < 4; ++q)
        *(ushort8*)&Bs[(fr16 + q * 32) * LSTR + fc16] = rb.h[q];
    } else {
#pragma unroll
      for (int q = 0; q < 8; ++q)
        *(u16x4*)&Bs[(fr32 + q * 16) * LSTR + fc32] = cvt4(rb.f[q]);
    }
    __syncthreads();

#pragma unroll
    for (int kk = 0; kk < 64; kk += 32) {
      bf16x8 af[4], bfr[4];
#pragma unroll
      for (int i = 0; i < 4; ++i)
        af[i] = *(const bf16x8*)&As[(wm + i * 16 + fm) * LSTR + kk + fk];
#pragma unroll
      for (int j = 0; j < 4; ++j)
        bfr[j] = *(const bf16x8*)&Bs[(wn + j * 16 + fm) * LSTR + kk + fk];
#pragma unroll
      for (int i = 0; i < 4; ++i)
#pragma unroll
        for (int j = 0; j < 4; ++j)
          acc[i][j] = __builtin_amdgcn_mfma_f32_16x16x32_bf16(af[i], bfr[j],
                                                              acc[i][j], 0, 0, 0);
    }
    ra = na;
    rb = nb;
  }

  // epilogue: C/D layout col=lane&15, row=(lane>>4)*4+r
  const int col = lane & 15;
  const int rb4 = (lane >> 4) * 4;
  float* Cp = Cpart + (size_t)s * M * N;
#pragma unroll
  for (int i = 0; i < 4; ++i) {
#pragma unroll
    for (int r = 0; r < 4; ++r) {
      int gm = m0 + wm + i * 16 + rb4 + r;
      if (gm >= M) continue;
#pragma unroll
      for (int j = 0; j < 4; ++j) {
        int gn = n0 + wn + j * 16 + col;
        if (gn < N) Cp[(size_t)gm * N + gn] = acc[i][j][r];
      }
    }
  }
}

// ---------------------------------------------------------------------------
// finalize: out = act(sum_s part[s] + bias[axis]) ; fp32 or bf16 out
// ---------------------------------------------------------------------------
__global__ __launch_bounds__(256) void finalize_kernel(
    const float* __restrict__ part, const float* __restrict__ bias,
    void* __restrict__ out, int M, int N, int S, int bias_on_n, int relu,
    int out_bf16) {
  int idx = blockIdx.x * blockDim.x + threadIdx.x;
  if (idx >= M * N) return;
  int m = idx / N;
  int n = idx - m * N;
  float v = 0.0f;
  for (int s2 = 0; s2 < S; ++s2) v += part[(size_t)s2 * M * N + idx];
  v += bias[bias_on_n ? n : m];
  if (relu) v = fmaxf(v, 0.0f);
  if (out_bf16)
    ((unsigned short*)out)[idx] = f2bf(v);
  else
    ((float*)out)[idx] = v;
}

// ---------------------------------------------------------------------------
// softmax over 81 classes; rois passthrough
// ---------------------------------------------------------------------------
__global__ __launch_bounds__(128) void softmax81(const float* __restrict__ in,
                                                 float* __restrict__ out) {
  int r = blockIdx.x * blockDim.x + threadIdx.x;
  if (r >= R_ROIS) return;
  const float* x = in + r * NCLS;
  float m = -1e30f;
  for (int i = 0; i < NCLS; ++i) m = fmaxf(m, x[i]);
  float s = 0.0f;
  for (int i = 0; i < NCLS; ++i) s += expf(x[i] - m);
  float inv = 1.0f / s;
  float* o = out + r * NCLS;
  for (int i = 0; i < NCLS; ++i) o[i] = expf(x[i] - m) * inv;
}

__global__ __launch_bounds__(256) void copy_rois(const float* __restrict__ rois,
                                                 float* __restrict__ out) {
  int i = blockIdx.x * blockDim.x + threadIdx.x;
  if (i < R_ROIS * 5) out[i] = rois[i];
}

// ---------------------------------------------------------------------------
// Launch
// ---------------------------------------------------------------------------
extern "C" void kernel_launch(void* const* d_in, const int* in_sizes, int n_in,
                              void* d_out, int out_size, void* d_ws,
                              size_t ws_size, hipStream_t stream) {
  const float* im = (const float*)d_in[0];
  const float* rois = (const float*)d_in[1];
  const float* w1 = (const float*)d_in[2];
  const float* b1 = (const float*)d_in[3];
  const float* w2 = (const float*)d_in[4];
  const float* b2 = (const float*)d_in[5];
  const float* w3 = (const float*)d_in[6];
  const float* b3 = (const float*)d_in[7];
  const float* w4 = (const float*)d_in[8];
  const float* b4 = (const float*)d_in[9];
  const float* fc6_w = (const float*)d_in[10];
  const float* fc6_b = (const float*)d_in[11];
  const float* fc7_w = (const float*)d_in[12];
  const float* fc7_b = (const float*)d_in[13];
  const float* cls_w = (const float*)d_in[14];
  const float* cls_b = (const float*)d_in[15];
  const float* bbox_w = (const float*)d_in[16];
  const float* bbox_b = (const float*)d_in[17];

  float* ws = (float*)d_ws;
  // layout (float offsets), total 24,576,000 floats = 98.3 MB:
  //   x1   @ 0          : 6,553,600   (64x320x320) -- overlaid later by
  //        pooledb @0 (3,763,200), h6b @3,763,200 (614,400),
  //        h7b @4,377,600 (614,400), cls_score @4,992,000 (24,300)
  //   x2   @ 6,553,600  : 3,276,800   (128x160x160)
  //   x3   @ 9,830,400  : 1,638,400   (256x80x80)
  //   x4   @ 11,468,800 :   819,200   (512x40x40)
  //   col  @ 12,288,000 : 7,372,800   (bf16: 14,745,600 ushorts, max conv2)
  //   cpart@ 19,660,800 : 4,915,200   (split-K partials, conv stages + heads)
  //   cpart_fc @ 5,120,000 : 17,203,200 max (fc6 S=14) -- region 5.12M..22.3M
  //        is dead during fc6/fc7 (x2/x3/x4/col all consumed before roi_align
  //        completes; pooledb/h6b/h7b/cls_score end at 5,016,300).
  float* x1 = ws;
  float* x2 = ws + 6553600;
  float* x3 = ws + 9830400;
  float* x4 = ws + 11468800;
  unsigned short* col = (unsigned short*)(ws + 12288000);
  float* cpart = ws + 19660800;
  float* cpart_fc = ws + 5120000;
  unsigned short* pooledb = (unsigned short*)ws;
  unsigned short* h6b = (unsigned short*)(ws + 3763200);
  unsigned short* h7b = (unsigned short*)(ws + 4377600);
  float* cls_score = ws + 4992000;

  float* out = (float*)d_out;
  float* out_rois = out;          // 1500
  float* out_cls = out + 1500;    // 24300
  float* out_bbox = out + 25800;  // 97200

  // conv1: (3,640,640) -> (64,320,320), direct
  conv_s2_relu<3, 4><<<dim3(400, 16), 256, 0, stream>>>(im, w1, b1, x1, 640,
                                                        640, 320, 320);

  // conv2: im2col + GEMM  M=128 N=25600 K=576
  im2col_bf16_staged<<<dim3(800, 1), 256, 0, stream>>>(x1, col, 64, 320, 320,
                                                       160, 160);
  gemm_mfma<false, true><<<dim3(200, 1, 1), 256, 0, stream>>>(
      w2, col, cpart, 128, 25600, 576, 576);
  finalize_kernel<<<dim3(12800), 256, 0, stream>>>(cpart, b2, x2, 128, 25600,
                                                   1, 0, 1, 0);

  // conv3: M=256 N=6400 K=1152, S=2
  im2col_bf16_staged<<<dim3(200, 2), 256, 0, stream>>>(x2, col, 128, 160, 160,
                                                       80, 80);
  gemm_mfma<false, true><<<dim3(50, 2, 2), 256, 0, stream>>>(
      w3, col, cpart, 256, 6400, 1152, 576);
  finalize_kernel<<<dim3(6400), 256, 0, stream>>>(cpart, b3, x3, 256, 6400, 2,
                                                  0, 1, 0);

  // conv4: M=512 N=1600 K=2304, S=4
  im2col_bf16_staged<<<dim3(50, 4), 256, 0, stream>>>(x3, col, 256, 80, 80,
                                                      40, 40);
  gemm_mfma<false, true><<<dim3(13, 4, 4), 256, 0, stream>>>(
      w4, col, cpart, 512, 1600, 2304, 576);
  finalize_kernel<<<dim3(3200), 256, 0, stream>>>(cpart, b4, x4, 512, 1600, 4,
                                                  0, 1, 0);

  // roi align -> bf16 pooled (300 x 25088)
  roi_align_kernel<<<dim3(29400), 256, 0, stream>>>(x4, rois, pooledb);

  // fc6: M=300 N=4096 K=25088, S=14 (Ksplit=1792=28*64) -> h6 (bf16, relu)
  gemm_mfma<true, false><<<dim3(32, 3, 14), 256, 0, stream>>>(
      pooledb, fc6_w, cpart_fc, 300, 4096, 25088, 1792);
  finalize_kernel<<<dim3(4800), 256, 0, stream>>>(cpart_fc, fc6_b, h6b, 300,
                                                  4096, 14, 1, 1, 1);

  // fc7: M=300 N=4096 K=4096, S=8 (Ksplit=512) -> h7 (bf16, relu)
  gemm_mfma<true, false><<<dim3(32, 3, 8), 256, 0, stream>>>(
      h6b, fc7_w, cpart_fc, 300, 4096, 4096, 512);
  finalize_kernel<<<dim3(4800), 256, 0, stream>>>(cpart_fc, fc7_b, h7b, 300,
                                                  4096, 8, 1, 1, 1);

  // cls head: M=300 N=81 K=4096, S=16 -> cls_score (fp32)
  gemm_mfma<true, false><<<dim3(1, 3, 16), 256, 0, stream>>>(
      h7b, cls_w, cpart, 300, 81, 4096, 256);
  finalize_kernel<<<dim3(95), 256, 0, stream>>>(cpart, cls_b, cls_score, 300,
                                                81, 16, 1, 0, 0);

  // bbox head: M=300 N=324 K=4096, S=16 -> out_bbox (fp32)
  gemm_mfma<true, false><<<dim3(3, 3, 16), 256, 0, stream>>>(
      h7b, bbox_w, cpart, 300, 324, 4096, 256);
  finalize_kernel<<<dim3(380), 256, 0, stream>>>(cpart, bbox_b, out_bbox, 300,
                                                 324, 16, 1, 0, 0);

  softmax81<<<dim3(3), 128, 0, stream>>>(cls_score, out_cls);
  copy_rois<<<dim3(6), 256, 0, stream>>>(rois, out_rois);
}